// Round 5
// baseline (4195.683 us; speedup 1.0000x reference)
//
#include <hip/hip_runtime.h>
#include <math.h>

constexpr int Bb  = 64;
constexpr int Tt  = 2048;
constexpr int INN = 128;
constexpr int HH  = 256;
constexpr int ROWS = Bb * Tt;   // 131072
constexpr int CH  = 64;         // pipeline chunk (rows of one batch)
constexpr int NCH = Tt / CH;    // 32 chunks
constexpr int PS  = HH + 4;     // 260: partial/B-tile row stride (2-way banks)

// Inter-role progress flags (rows completed per batch). Monotonic within one
// kernel execution; re-zeroed by ih_gemm (previous kernel in stream) each run.
__device__ int g_flag0[Bb];     // producer  -> gemm
__device__ int g_flag1[Bb];     // gemm      -> consumer

// ---------------------------------------------------------------------------
// xp0 GEMM: out[row][j] = sum_k x[row][k]*W[j][k] + b1[j] + b2[j], K=128.
// 256 threads, 64x256 tile, 8x8 per thread. b_lds stride 260 (2-way writes).
// Block 0 additionally zeroes the pipeline flags for this run.
// ---------------------------------------------------------------------------
__global__ __launch_bounds__(256) void ih_gemm(const float* in, const float* W,
                                               const float* bias1, const float* bias2,
                                               float* out)
{
    __shared__ float a_lds[16][68];
    __shared__ float b_lds[16][260];

    const int tid = threadIdx.x;
    if (blockIdx.x == 0 && tid < Bb) { g_flag0[tid] = 0; g_flag1[tid] = 0; }

    const int tx  = tid & 31;
    const int ty  = tid >> 5;
    const int row0 = blockIdx.x * 64;

    float acc[8][8];
#pragma unroll
    for (int r = 0; r < 8; ++r)
#pragma unroll
        for (int c = 0; c < 8; ++c) acc[r][c] = 0.f;

    for (int k0 = 0; k0 < INN; k0 += 16) {
#pragma unroll
        for (int i = 0; i < 4; ++i) {
            int e = i * 256 + tid;
            int r = e >> 4, kk = e & 15;
            a_lds[kk][r] = in[(row0 + r) * INN + k0 + kk];
        }
#pragma unroll
        for (int i = 0; i < 16; ++i) {
            int e = i * 256 + tid;
            int j = e >> 4, kk = e & 15;
            b_lds[kk][j] = W[j * INN + k0 + kk];
        }
        __syncthreads();

#pragma unroll
        for (int kk = 0; kk < 16; ++kk) {
            float4 a0 = *(const float4*)&a_lds[kk][ty * 8];
            float4 a1 = *(const float4*)&a_lds[kk][ty * 8 + 4];
            float4 b0 = *(const float4*)&b_lds[kk][tx * 8];
            float4 b1 = *(const float4*)&b_lds[kk][tx * 8 + 4];
            float av[8] = {a0.x, a0.y, a0.z, a0.w, a1.x, a1.y, a1.z, a1.w};
            float bv[8] = {b0.x, b0.y, b0.z, b0.w, b1.x, b1.y, b1.z, b1.w};
#pragma unroll
            for (int r = 0; r < 8; ++r)
#pragma unroll
                for (int c = 0; c < 8; ++c)
                    acc[r][c] += av[r] * bv[c];
        }
        __syncthreads();
    }

    float bsum[8];
#pragma unroll
    for (int c = 0; c < 8; ++c) {
        int j = tx * 8 + c;
        bsum[c] = bias1[j] + bias2[j];
    }
#pragma unroll
    for (int r = 0; r < 8; ++r) {
        int row = row0 + ty * 8 + r;
        float4 o0 = make_float4(acc[r][0] + bsum[0], acc[r][1] + bsum[1],
                                acc[r][2] + bsum[2], acc[r][3] + bsum[3]);
        float4 o1 = make_float4(acc[r][4] + bsum[4], acc[r][5] + bsum[5],
                                acc[r][6] + bsum[6], acc[r][7] + bsum[7]);
        *(float4*)&out[row * HH + tx * 8]     = o0;
        *(float4*)&out[row * HH + tx * 8 + 4] = o1;
    }
}

// ---------------------------------------------------------------------------
// fast tanh, clamp-free: x->+inf: e=inf, rcp=0 -> 1; x->-inf: e=0 -> -1.
// ---------------------------------------------------------------------------
__device__ __forceinline__ float fast_tanh(float x)
{
    float e = __builtin_amdgcn_exp2f(x * 2.8853900817779268f);  // 2*log2(e)
    return fmaf(-2.0f, __builtin_amdgcn_rcpf(e + 1.0f), 1.0f);
}

__device__ __forceinline__ float fold16(float s)
{
    int v = __builtin_amdgcn_ds_swizzle(__float_as_int(s), 0x401F);  // xor 16
    return s + __int_as_float(v);
}

__device__ __forceinline__ float fold32(float s)
{
#if __has_builtin(__builtin_amdgcn_permlane32_swap)
    typedef unsigned uint2v __attribute__((ext_vector_type(2)));
    uint2v r = __builtin_amdgcn_permlane32_swap(__float_as_uint(s), __float_as_uint(s),
                                                false, false);
    return __uint_as_float(r[0]) + __uint_as_float(r[1]);
#else
    return s + __shfl_xor(s, 32, 64);
#endif
}

// ---------------------------------------------------------------------------
// One recurrence step (v4-verified dataflow): reads partials from rd,
// writes next-step partials to wr, commits h over xp[t] (in-place), ONE
// barrier. xg carries xp[t]; prefetches *pr into xg for the next step.
// ---------------------------------------------------------------------------
__device__ __forceinline__ void rnn_step(const float* rd, float* wr,
                                         float*& pw, const float* pr,
                                         float& xg, const float (&wreg)[4][16],
                                         bool lane_lt16)
{
    float xg2 = *pr;

    float s0 = rd[0 * PS], s1 = rd[1 * PS], s2 = rd[2 * PS], s3 = rd[3 * PS];
    float s = (s0 + s1) + (s2 + s3);
    s = fold16(s);
    s = fold32(s);

    float hv = fast_tanh(s + xg);
    if (lane_lt16) *pw = hv;

    float p0 = 0.f, p1 = 0.f, p2 = 0.f, p3 = 0.f;
#pragma unroll
    for (int c = 0; c < 16; ++c) {
        float hcv = __int_as_float(__builtin_amdgcn_readlane(__float_as_int(hv), c));
        p0 = fmaf(wreg[0][c], hcv, p0);
        p1 = fmaf(wreg[1][c], hcv, p1);
        p2 = fmaf(wreg[2][c], hcv, p2);
        p3 = fmaf(wreg[3][c], hcv, p3);
    }
    *(float4*)wr = make_float4(p0, p1, p2, p3);

    __syncthreads();
    xg = xg2;
    pw += HH;
}

// ---------------------------------------------------------------------------
// Recurrence role (producer: layer 0 / consumer: layer 1), chunked.
// PROD: releases g_flag0[b] after each 64-row chunk of h written.
// !PROD: acquires g_flag1[b] before each chunk; reloads xg fresh after the
//        acquire (cross-chunk prefetch may be stale and is discarded).
// ---------------------------------------------------------------------------
template <bool PROD>
__device__ void rnn_role(float* xpb, const float* Whh, float* sh, int b)
{
    float* pbufA = sh;
    float* pbufB = sh + 16 * PS;

    const int tid = threadIdx.x;
    const int w   = tid >> 6;
    const int l   = tid & 63;
    const int g   = l >> 4;
    const int jr  = 16 * w + (l & 15);
    const bool lane_lt16 = (l < 16);

    float wreg[4][16];
#pragma unroll
    for (int r = 0; r < 4; ++r) {
        const float4* wp = (const float4*)&Whh[(size_t)(4 * l + r) * HH + 16 * w];
#pragma unroll
        for (int q = 0; q < 4; ++q) {
            float4 v = wp[q];
            wreg[r][4 * q + 0] = v.x;
            wreg[r][4 * q + 1] = v.y;
            wreg[r][4 * q + 2] = v.z;
            wreg[r][4 * q + 3] = v.w;
        }
    }

    const float* rdA = &pbufA[4 * g * PS + jr];
    const float* rdB = &pbufB[4 * g * PS + jr];
    float*       wrA = &pbufA[w * PS + 4 * l];

    *(float4*)wrA = make_float4(0.f, 0.f, 0.f, 0.f);   // h_{-1} = 0
    float xg = PROD ? xpb[jr] : 0.f;    // consumer: overwritten post-acquire
    float* pw = xpb + jr;
    const float* pr = xpb + HH + jr;
    __syncthreads();

    float* wrAx = &pbufA[w * PS + 4 * l];
    float* wrBx = &pbufB[w * PS + 4 * l];

#pragma unroll 1
    for (int c = 0; c < NCH; ++c) {
        if (!PROD) {
            while (__hip_atomic_load(&g_flag1[b], __ATOMIC_ACQUIRE,
                                     __HIP_MEMORY_SCOPE_AGENT) < (c + 1) * CH)
                __builtin_amdgcn_s_sleep(16);
            xg = xpb[(size_t)c * CH * HH + jr];
        }
        const int npairs = (c == NCH - 1) ? (CH / 2 - 1) : (CH / 2);
#pragma unroll 1
        for (int p = 0; p < npairs; ++p) {
            rnn_step(rdA, wrBx, pw, pr, xg, wreg, lane_lt16); pr += HH;
            rnn_step(rdB, wrAx, pw, pr, xg, wreg, lane_lt16); pr += HH;
        }
        if (c == NCH - 1) {   // final pair: prefetch clamped to row Tt-1
            rnn_step(rdA, wrBx, pw, pr, xg, wreg, lane_lt16);
            rnn_step(rdB, wrAx, pw, pr, xg, wreg, lane_lt16);
        }
        if (PROD && tid == 0) {
            __threadfence();
            __hip_atomic_store(&g_flag0[b], (c + 1) * CH,
                               __ATOMIC_RELEASE, __HIP_MEMORY_SCOPE_AGENT);
        }
    }
}

// ---------------------------------------------------------------------------
// GEMM role v2: xp1 chunk = h1 chunk @ W_ih1^T + b, in place.
//  - compute: 256 threads (waves 0-3), 8x8 register tile, 64x256 output.
//    Per kk: 4 b128 LDS reads -> 64 FMA (16 FMA/read, 2x v5's ratio).
//  - staging: ALL threads double-buffer A(64x16)+B(256x16) tiles; stage of
//    k0-step s+1 overlaps compute of s; ONE barrier per k0-step.
//  - strides: A 68, B 260 -> all LDS writes 2-way (free), reads
//    contiguous/broadcast (conflict-free).
// In-place safe: all A reads of a chunk happen in k-loop staging, epilogue
// writes happen after (program order + final barrier before flag release).
// ---------------------------------------------------------------------------
constexpr int ASZ = 16 * 68;    // 1088 words per A buffer
constexpr int BSZ = 16 * 260;   // 4160 words per B buffer

__device__ void gemm_role(float* ws, const float* W,
                          const float* b1, const float* b2, float* sh, int b)
{
    float* Ad = sh;              // [2][16][68]
    float* Bd = sh + 2 * ASZ;    // [2][16][260]

    const int tid  = threadIdx.x;
    const bool comp = (tid < 256);
    const int tx = tid & 31;          // col-group: cols 8tx..8tx+7
    const int ty = (tid >> 5) & 7;    // row-group: rows 8ty..8ty+7

    float bs[8];
    if (comp) {
#pragma unroll
        for (int q = 0; q < 8; ++q) bs[q] = b1[tx * 8 + q] + b2[tx * 8 + q];
    }

    const int sr = tid >> 4, sk = tid & 15;   // A staging coords (1/thread)

#pragma unroll 1
    for (int c = 0; c < NCH; ++c) {
        while (__hip_atomic_load(&g_flag0[b], __ATOMIC_ACQUIRE,
                                 __HIP_MEMORY_SCOPE_AGENT) < (c + 1) * CH)
            __builtin_amdgcn_s_sleep(16);

        float* Ab = ws + ((size_t)b * Tt + (size_t)c * CH) * HH;

        // prologue: stage k0=0 into buffer 0
        Ad[sk * 68 + sr] = Ab[(size_t)sr * HH + sk];
#pragma unroll
        for (int i = 0; i < 4; ++i) {
            int e = i * 1024 + tid;
            int j = e >> 4, k2 = e & 15;
            Bd[k2 * 260 + j] = W[j * HH + k2];
        }
        __syncthreads();

        float acc[8][8];
        if (comp) {
#pragma unroll
            for (int r = 0; r < 8; ++r)
#pragma unroll
                for (int q = 0; q < 8; ++q) acc[r][q] = 0.f;
        }

#pragma unroll 1
        for (int s = 0; s < 16; ++s) {
            const int cur = s & 1;
            if (s < 15) {    // stage k0-step s+1 into the other buffer
                const int k0 = (s + 1) * 16;
                Ad[(cur ^ 1) * ASZ + sk * 68 + sr] = Ab[(size_t)sr * HH + k0 + sk];
#pragma unroll
                for (int i = 0; i < 4; ++i) {
                    int e = i * 1024 + tid;
                    int j = e >> 4, k2 = e & 15;
                    Bd[(cur ^ 1) * BSZ + k2 * 260 + j] = W[j * HH + k0 + k2];
                }
            }
            if (comp) {
                const float* Ac = Ad + cur * ASZ;
                const float* Bc = Bd + cur * BSZ;
#pragma unroll
                for (int kk = 0; kk < 16; ++kk) {
                    float4 a0 = *(const float4*)&Ac[kk * 68 + ty * 8];
                    float4 a1 = *(const float4*)&Ac[kk * 68 + ty * 8 + 4];
                    float4 c0 = *(const float4*)&Bc[kk * 260 + tx * 8];
                    float4 c1 = *(const float4*)&Bc[kk * 260 + tx * 8 + 4];
                    float av[8] = {a0.x, a0.y, a0.z, a0.w, a1.x, a1.y, a1.z, a1.w};
                    float bv[8] = {c0.x, c0.y, c0.z, c0.w, c1.x, c1.y, c1.z, c1.w};
#pragma unroll
                    for (int r = 0; r < 8; ++r)
#pragma unroll
                        for (int q = 0; q < 8; ++q)
                            acc[r][q] = fmaf(av[r], bv[q], acc[r][q]);
                }
                if (s == 15) {   // epilogue: in-place 8x8 tile write
#pragma unroll
                    for (int r = 0; r < 8; ++r) {
                        float* orow = Ab + (size_t)(ty * 8 + r) * HH + tx * 8;
                        *(float4*)orow =
                            make_float4(acc[r][0] + bs[0], acc[r][1] + bs[1],
                                        acc[r][2] + bs[2], acc[r][3] + bs[3]);
                        *(float4*)(orow + 4) =
                            make_float4(acc[r][4] + bs[4], acc[r][5] + bs[5],
                                        acc[r][6] + bs[6], acc[r][7] + bs[7]);
                    }
                }
            }
            __syncthreads();   // also drains epilogue stores (vmcnt) at s=15
        }
        if (tid == 0) {
            __threadfence();
            __hip_atomic_store(&g_flag1[b], (c + 1) * CH,
                               __ATOMIC_RELEASE, __HIP_MEMORY_SCOPE_AGENT);
        }
    }
}

// ---------------------------------------------------------------------------
// Pipelined fused kernel: blocks 0..63 producer (layer-0 recurrence),
// 64..127 gemm (xp1 tiles), 128..191 consumer (layer-1 recurrence).
// 192 blocks <= 256 CUs, wait graph is a DAG => no deadlock.
// Shared: union of roles -> max(8320, 2*ASZ + 2*BSZ = 10496) words.
// ---------------------------------------------------------------------------
__global__ __launch_bounds__(1024, 4) void pipeline_kernel(
        float* ws, const float* Whh0, const float* Wih1,
        const float* bih1, const float* bhh1, const float* Whh1)
{
    __shared__ __attribute__((aligned(16))) float sh[2 * ASZ + 2 * BSZ];

    const int role = blockIdx.x >> 6;
    const int b    = blockIdx.x & 63;

    if (role == 0)
        rnn_role<true>(ws + (size_t)b * Tt * HH, Whh0, sh, b);
    else if (role == 1)
        gemm_role(ws, Wih1, bih1, bhh1, sh, b);
    else
        rnn_role<false>(ws + (size_t)b * Tt * HH, Whh1, sh, b);
}

// ---------------------------------------------------------------------------
// FC: out[b] = dot(h2[b][T-1][:], W_fc) + b_fc.  One wave per batch.
// ---------------------------------------------------------------------------
__global__ __launch_bounds__(64) void fc_kernel(const float* h2, const float* Wfc,
                                                const float* bfc, float* out)
{
    const int b = blockIdx.x;
    const int l = threadIdx.x;
    const float* hrow = h2 + ((size_t)b * Tt + (Tt - 1)) * HH;
    float4 hv = *(const float4*)&hrow[4 * l];
    float4 wv = *(const float4*)&Wfc[4 * l];
    float p = hv.x * wv.x + hv.y * wv.y + hv.z * wv.z + hv.w * wv.w;
#pragma unroll
    for (int off = 32; off > 0; off >>= 1) p += __shfl_down(p, off, 64);
    if (l == 0) out[b] = p + bfc[0];
}

// ---------------------------------------------------------------------------
extern "C" void kernel_launch(void* const* d_in, const int* in_sizes, int n_in,
                              void* d_out, int out_size, void* d_ws, size_t ws_size,
                              hipStream_t stream)
{
    const float* x     = (const float*)d_in[0];
    const float* W_ih0 = (const float*)d_in[1];
    const float* W_hh0 = (const float*)d_in[2];
    const float* b_ih0 = (const float*)d_in[3];
    const float* b_hh0 = (const float*)d_in[4];
    const float* W_ih1 = (const float*)d_in[5];
    const float* W_hh1 = (const float*)d_in[6];
    const float* b_ih1 = (const float*)d_in[7];
    const float* b_hh1 = (const float*)d_in[8];
    const float* W_fc  = (const float*)d_in[9];
    const float* b_fc  = (const float*)d_in[10];
    float* ws  = (float*)d_ws;                 // B*T*H floats (128 MiB)
    float* out = (float*)d_out;

    // 1) xp0 = x @ W_ih0^T + b_ih0 + b_hh0  (+ zero pipeline flags)
    ih_gemm<<<ROWS / 64, 256, 0, stream>>>(x, W_ih0, b_ih0, b_hh0, ws);
    // 2) fused pipeline: L0 recurrence -> chunked xp1 GEMM -> L1 recurrence,
    //    all in-place in ws; ws ends as the h2 sequence.
    pipeline_kernel<<<192, 1024, 0, stream>>>(ws, W_hh0, W_ih1, b_ih1, b_hh1, W_hh1);
    // 3) out = h2[:, T-1, :] @ W_fc^T + b_fc
    fc_kernel<<<Bb, 64, 0, stream>>>(ws, W_fc, b_fc, out);
}

// Round 6
// 2160.574 us; speedup vs baseline: 1.9419x; 1.9419x over previous
//
#include <hip/hip_runtime.h>
#include <math.h>

constexpr int Bb  = 64;
constexpr int Tt  = 2048;
constexpr int INN = 128;
constexpr int HH  = 256;
constexpr int ROWS = Bb * Tt;   // 131072
constexpr int CH  = 64;         // pipeline chunk (rows of one batch)
constexpr int NCH = Tt / CH;    // 32 chunks
constexpr int PS  = HH + 4;     // 260: partial-buffer row stride (2-way banks)

// Inter-role progress flags (rows completed per batch). Monotonic within one
// kernel execution; re-zeroed by ih_gemm (previous kernel in stream) each run.
__device__ int g_flag0[Bb];     // producer  -> gemm
__device__ int g_flag1[Bb];     // gemm      -> consumer

// ---------------------------------------------------------------------------
// xp0 GEMM: out[row][j] = sum_k x[row][k]*W[j][k] + b1[j] + b2[j], K=128.
// 256 threads, 64x256 tile, 8x8 per thread (v5-verified machinery).
// Block 0 additionally zeroes the pipeline flags for this run.
// ---------------------------------------------------------------------------
__global__ __launch_bounds__(256) void ih_gemm(const float* in, const float* W,
                                               const float* bias1, const float* bias2,
                                               float* out)
{
    __shared__ float a_lds[16][68];
    __shared__ float b_lds[16][260];

    const int tid = threadIdx.x;
    if (blockIdx.x == 0 && tid < Bb) { g_flag0[tid] = 0; g_flag1[tid] = 0; }

    const int tx  = tid & 31;
    const int ty  = tid >> 5;
    const int row0 = blockIdx.x * 64;

    float acc[8][8];
#pragma unroll
    for (int r = 0; r < 8; ++r)
#pragma unroll
        for (int c = 0; c < 8; ++c) acc[r][c] = 0.f;

    for (int k0 = 0; k0 < INN; k0 += 16) {
#pragma unroll
        for (int i = 0; i < 4; ++i) {
            int e = i * 256 + tid;
            int r = e >> 4, kk = e & 15;
            a_lds[kk][r] = in[(row0 + r) * INN + k0 + kk];
        }
#pragma unroll
        for (int i = 0; i < 16; ++i) {
            int e = i * 256 + tid;
            int j = e >> 4, kk = e & 15;
            b_lds[kk][j] = W[j * INN + k0 + kk];
        }
        __syncthreads();

#pragma unroll
        for (int kk = 0; kk < 16; ++kk) {
            float4 a0 = *(const float4*)&a_lds[kk][ty * 8];
            float4 a1 = *(const float4*)&a_lds[kk][ty * 8 + 4];
            float4 b0 = *(const float4*)&b_lds[kk][tx * 8];
            float4 b1 = *(const float4*)&b_lds[kk][tx * 8 + 4];
            float av[8] = {a0.x, a0.y, a0.z, a0.w, a1.x, a1.y, a1.z, a1.w};
            float bv[8] = {b0.x, b0.y, b0.z, b0.w, b1.x, b1.y, b1.z, b1.w};
#pragma unroll
            for (int r = 0; r < 8; ++r)
#pragma unroll
                for (int c = 0; c < 8; ++c)
                    acc[r][c] += av[r] * bv[c];
        }
        __syncthreads();
    }

    float bsum[8];
#pragma unroll
    for (int c = 0; c < 8; ++c) {
        int j = tx * 8 + c;
        bsum[c] = bias1[j] + bias2[j];
    }
#pragma unroll
    for (int r = 0; r < 8; ++r) {
        int row = row0 + ty * 8 + r;
        float4 o0 = make_float4(acc[r][0] + bsum[0], acc[r][1] + bsum[1],
                                acc[r][2] + bsum[2], acc[r][3] + bsum[3]);
        float4 o1 = make_float4(acc[r][4] + bsum[4], acc[r][5] + bsum[5],
                                acc[r][6] + bsum[6], acc[r][7] + bsum[7]);
        *(float4*)&out[row * HH + tx * 8]     = o0;
        *(float4*)&out[row * HH + tx * 8 + 4] = o1;
    }
}

// ---------------------------------------------------------------------------
// fast tanh, clamp-free: x->+inf: e=inf, rcp=0 -> 1; x->-inf: e=0 -> -1.
// ---------------------------------------------------------------------------
__device__ __forceinline__ float fast_tanh(float x)
{
    float e = __builtin_amdgcn_exp2f(x * 2.8853900817779268f);  // 2*log2(e)
    return fmaf(-2.0f, __builtin_amdgcn_rcpf(e + 1.0f), 1.0f);
}

__device__ __forceinline__ float fold16(float s)
{
    int v = __builtin_amdgcn_ds_swizzle(__float_as_int(s), 0x401F);  // xor 16
    return s + __int_as_float(v);
}

__device__ __forceinline__ float fold32(float s)
{
#if __has_builtin(__builtin_amdgcn_permlane32_swap)
    typedef unsigned uint2v __attribute__((ext_vector_type(2)));
    uint2v r = __builtin_amdgcn_permlane32_swap(__float_as_uint(s), __float_as_uint(s),
                                                false, false);
    return __uint_as_float(r[0]) + __uint_as_float(r[1]);
#else
    return s + __shfl_xor(s, 32, 64);
#endif
}

// weights load: wreg[r][c] = W[(4l + r)*HH + 16w + c]
__device__ __forceinline__ void load_wreg(const float* W, int l, int w,
                                          float (&wreg)[4][16])
{
#pragma unroll
    for (int r = 0; r < 4; ++r) {
        const float4* wp = (const float4*)&W[(size_t)(4 * l + r) * HH + 16 * w];
#pragma unroll
        for (int q = 0; q < 4; ++q) {
            float4 v = wp[q];
            wreg[r][4 * q + 0] = v.x;
            wreg[r][4 * q + 1] = v.y;
            wreg[r][4 * q + 2] = v.z;
            wreg[r][4 * q + 3] = v.w;
        }
    }
}

// MAC: partials of (W-chunk) * broadcast(xg) -> b128 write to wr
__device__ __forceinline__ void mac_partials(float xg, const float (&wreg)[4][16],
                                             float* wr)
{
    float p0 = 0.f, p1 = 0.f, p2 = 0.f, p3 = 0.f;
#pragma unroll
    for (int c = 0; c < 16; ++c) {
        float hcv = __int_as_float(__builtin_amdgcn_readlane(__float_as_int(xg), c));
        p0 = fmaf(wreg[0][c], hcv, p0);
        p1 = fmaf(wreg[1][c], hcv, p1);
        p2 = fmaf(wreg[2][c], hcv, p2);
        p3 = fmaf(wreg[3][c], hcv, p3);
    }
    *(float4*)wr = make_float4(p0, p1, p2, p3);
}

// ---------------------------------------------------------------------------
// One recurrence step (v4-verified dataflow): reads partials from rd,
// writes next-step partials to wr, commits h over xp[t] (in-place), ONE
// barrier. xg carries xp[t]; prefetches *pr into xg for the next step.
// ---------------------------------------------------------------------------
__device__ __forceinline__ void rnn_step(const float* rd, float* wr,
                                         float*& pw, const float* pr,
                                         float& xg, const float (&wreg)[4][16],
                                         bool lane_lt16)
{
    float xg2 = *pr;

    float s0 = rd[0 * PS], s1 = rd[1 * PS], s2 = rd[2 * PS], s3 = rd[3 * PS];
    float s = (s0 + s1) + (s2 + s3);
    s = fold16(s);
    s = fold32(s);

    float hv = fast_tanh(s + xg);
    if (lane_lt16) *pw = hv;

    mac_partials(hv, wreg, wr);

    __syncthreads();
    xg = xg2;
    pw += HH;
}

// ---------------------------------------------------------------------------
// Recurrence role (producer: layer 0 / consumer: layer 1), chunked.
// PROD: releases g_flag0[b] after each 64-row chunk of h written.
// !PROD: acquires g_flag1[b] before each chunk; reloads xg fresh after the
//        acquire (cross-chunk prefetch may be stale and is discarded).
// ---------------------------------------------------------------------------
template <bool PROD>
__device__ void rnn_role(float* xpb, const float* Whh, float* sh, int b)
{
    float* pbufA = sh;
    float* pbufB = sh + 16 * PS;

    const int tid = threadIdx.x;
    const int w   = tid >> 6;
    const int l   = tid & 63;
    const int g   = l >> 4;
    const int jr  = 16 * w + (l & 15);
    const bool lane_lt16 = (l < 16);

    float wreg[4][16];
    load_wreg(Whh, l, w, wreg);

    const float* rdA = &pbufA[4 * g * PS + jr];
    const float* rdB = &pbufB[4 * g * PS + jr];
    float*       wrA = &pbufA[w * PS + 4 * l];
    float*       wrB = &pbufB[w * PS + 4 * l];

    *(float4*)wrA = make_float4(0.f, 0.f, 0.f, 0.f);   // h_{-1} = 0
    float xg = PROD ? xpb[jr] : 0.f;    // consumer: overwritten post-acquire
    float* pw = xpb + jr;
    const float* pr = xpb + HH + jr;
    __syncthreads();

#pragma unroll 1
    for (int c = 0; c < NCH; ++c) {
        if (!PROD) {
            while (__hip_atomic_load(&g_flag1[b], __ATOMIC_ACQUIRE,
                                     __HIP_MEMORY_SCOPE_AGENT) < (c + 1) * CH)
                __builtin_amdgcn_s_sleep(16);
            xg = xpb[(size_t)c * CH * HH + jr];
        }
        const int npairs = (c == NCH - 1) ? (CH / 2 - 1) : (CH / 2);
#pragma unroll 1
        for (int p = 0; p < npairs; ++p) {
            rnn_step(rdA, wrB, pw, pr, xg, wreg, lane_lt16); pr += HH;
            rnn_step(rdB, wrA, pw, pr, xg, wreg, lane_lt16); pr += HH;
        }
        if (c == NCH - 1) {   // final pair: prefetch clamped to row Tt-1
            rnn_step(rdA, wrB, pw, pr, xg, wreg, lane_lt16);
            rnn_step(rdB, wrA, pw, pr, xg, wreg, lane_lt16);
        }
        if (PROD && tid == 0) {
            __threadfence();
            __hip_atomic_store(&g_flag0[b], (c + 1) * CH,
                               __ATOMIC_RELEASE, __HIP_MEMORY_SCOPE_AGENT);
        }
    }
}

// ---------------------------------------------------------------------------
// GEMM role v3 — matvec formulation (producer dataflow without feedback):
// xp1[r][j] = sum_k Wih1[j][k] * h1[r][k] + bias[j], row by row, in place.
//  - wreg (stationary, 64 VGPRs) = Wih1 chunk, same layout as rnn_role.
//  - row r enters as xg = h1[r][jr] (lane-spread global read, prefetched
//    one row ahead); broadcast via readlane inside mac_partials.
//  - phase p (p=0..64): reduce row p-1 partials (+bias, store in place),
//    MAC row p partials into the other buffer, ONE barrier.
//  - rows independent -> no serial chain; latency fully pipelined.
// In-place safe: row p's values are consumed (xg read) before its store;
// all partial-buffer read/write hazards separated by the per-phase barrier.
// No LDS tiles, no acc array -> no spill, no staging bank conflicts.
// ---------------------------------------------------------------------------
__device__ __forceinline__ void gemm_phase(const float* rd, float* wr,
                                           float*& pw, const float* pr,
                                           float& xg, const float (&wreg)[4][16],
                                           float bsc, bool lane_lt16)
{
    float xg2 = *pr;                 // prefetch row p+1

    float s0 = rd[0 * PS], s1 = rd[1 * PS], s2 = rd[2 * PS], s3 = rd[3 * PS];
    float s = (s0 + s1) + (s2 + s3);
    s = fold16(s);
    s = fold32(s);
    if (lane_lt16) *pw = s + bsc;    // commit xp1[row p-1][jr]

    mac_partials(xg, wreg, wr);      // partials for row p

    __syncthreads();
    xg = xg2;
    pw += HH;
}

__device__ void gemm_role(float* ws, const float* W,
                          const float* b1, const float* b2, float* sh, int b)
{
    float* pbufA = sh;
    float* pbufB = sh + 16 * PS;

    const int tid = threadIdx.x;
    const int w   = tid >> 6;
    const int l   = tid & 63;
    const int g   = l >> 4;
    const int jr  = 16 * w + (l & 15);
    const bool lane_lt16 = (l < 16);

    float wreg[4][16];
    load_wreg(W, l, w, wreg);
    const float bsc = b1[jr] + b2[jr];

    const float* rdA = &pbufA[4 * g * PS + jr];
    const float* rdB = &pbufB[4 * g * PS + jr];
    float*       wrA = &pbufA[w * PS + 4 * l];
    float*       wrB = &pbufB[w * PS + 4 * l];

#pragma unroll 1
    for (int c = 0; c < NCH; ++c) {
        while (__hip_atomic_load(&g_flag0[b], __ATOMIC_ACQUIRE,
                                 __HIP_MEMORY_SCOPE_AGENT) < (c + 1) * CH)
            __builtin_amdgcn_s_sleep(16);

        float* Ab = ws + ((size_t)b * Tt + (size_t)c * CH) * HH;

        // phase 0 (peeled): MAC row 0, no reduce/store
        float xg  = Ab[jr];              // row 0, fresh post-acquire
        float xg2 = Ab[HH + jr];         // prefetch row 1
        mac_partials(xg, wreg, wrB);
        __syncthreads();
        xg = xg2;

        float* pw = Ab + jr;             // store ptr, starts at row 0
        const float* pr = Ab + 2 * HH + jr;   // prefetch ptr (row 2)

        // phases 1..62 (31 pairs): odd reads B writes A, even reads A writes B
#pragma unroll 1
        for (int p = 0; p < 31; ++p) {
            gemm_phase(rdB, wrA, pw, pr, xg, wreg, bsc, lane_lt16); pr += HH;
            gemm_phase(rdA, wrB, pw, pr, xg, wreg, bsc, lane_lt16); pr += HH;
        }
        // phase 63: prefetch clamped to row 63 (value discarded at chunk end)
        gemm_phase(rdB, wrA, pw, pr - HH, xg, wreg, bsc, lane_lt16);

        // tail phase 64: reduce row 63 only
        {
            float s0 = rdA[0 * PS], s1 = rdA[1 * PS];
            float s2 = rdA[2 * PS], s3 = rdA[3 * PS];
            float s = (s0 + s1) + (s2 + s3);
            s = fold16(s);
            s = fold32(s);
            if (lane_lt16) *pw = s + bsc;
            __syncthreads();
        }

        if (tid == 0) {
            __threadfence();
            __hip_atomic_store(&g_flag1[b], (c + 1) * CH,
                               __ATOMIC_RELEASE, __HIP_MEMORY_SCOPE_AGENT);
        }
    }
}

// ---------------------------------------------------------------------------
// Pipelined fused kernel: blocks 0..63 producer (layer-0 recurrence),
// 64..127 gemm (xp1 matvecs), 128..191 consumer (layer-1 recurrence).
// 192 blocks <= 256 CUs, wait graph is a DAG => no deadlock.
// ---------------------------------------------------------------------------
__global__ __launch_bounds__(1024, 4) void pipeline_kernel(
        float* ws, const float* Whh0, const float* Wih1,
        const float* bih1, const float* bhh1, const float* Whh1)
{
    __shared__ __attribute__((aligned(16))) float sh[2 * 16 * PS];  // 33280 B

    const int role = blockIdx.x >> 6;
    const int b    = blockIdx.x & 63;

    if (role == 0)
        rnn_role<true>(ws + (size_t)b * Tt * HH, Whh0, sh, b);
    else if (role == 1)
        gemm_role(ws, Wih1, bih1, bhh1, sh, b);
    else
        rnn_role<false>(ws + (size_t)b * Tt * HH, Whh1, sh, b);
}

// ---------------------------------------------------------------------------
// FC: out[b] = dot(h2[b][T-1][:], W_fc) + b_fc.  One wave per batch.
// ---------------------------------------------------------------------------
__global__ __launch_bounds__(64) void fc_kernel(const float* h2, const float* Wfc,
                                                const float* bfc, float* out)
{
    const int b = blockIdx.x;
    const int l = threadIdx.x;
    const float* hrow = h2 + ((size_t)b * Tt + (Tt - 1)) * HH;
    float4 hv = *(const float4*)&hrow[4 * l];
    float4 wv = *(const float4*)&Wfc[4 * l];
    float p = hv.x * wv.x + hv.y * wv.y + hv.z * wv.z + hv.w * wv.w;
#pragma unroll
    for (int off = 32; off > 0; off >>= 1) p += __shfl_down(p, off, 64);
    if (l == 0) out[b] = p + bfc[0];
}

// ---------------------------------------------------------------------------
extern "C" void kernel_launch(void* const* d_in, const int* in_sizes, int n_in,
                              void* d_out, int out_size, void* d_ws, size_t ws_size,
                              hipStream_t stream)
{
    const float* x     = (const float*)d_in[0];
    const float* W_ih0 = (const float*)d_in[1];
    const float* W_hh0 = (const float*)d_in[2];
    const float* b_ih0 = (const float*)d_in[3];
    const float* b_hh0 = (const float*)d_in[4];
    const float* W_ih1 = (const float*)d_in[5];
    const float* W_hh1 = (const float*)d_in[6];
    const float* b_ih1 = (const float*)d_in[7];
    const float* b_hh1 = (const float*)d_in[8];
    const float* W_fc  = (const float*)d_in[9];
    const float* b_fc  = (const float*)d_in[10];
    float* ws  = (float*)d_ws;                 // B*T*H floats (128 MiB)
    float* out = (float*)d_out;

    // 1) xp0 = x @ W_ih0^T + b_ih0 + b_hh0  (+ zero pipeline flags)
    ih_gemm<<<ROWS / 64, 256, 0, stream>>>(x, W_ih0, b_ih0, b_hh0, ws);
    // 2) fused pipeline: L0 recurrence -> chunked xp1 matvec -> L1 recurrence,
    //    all in-place in ws; ws ends as the h2 sequence.
    pipeline_kernel<<<192, 1024, 0, stream>>>(ws, W_hh0, W_ih1, b_ih1, b_hh1, W_hh1);
    // 3) out = h2[:, T-1, :] @ W_fc^T + b_fc
    fc_kernel<<<Bb, 64, 0, stream>>>(ws, W_fc, b_fc, out);
}

// Round 7
// 1872.477 us; speedup vs baseline: 2.2407x; 1.1539x over previous
//
#include <hip/hip_runtime.h>
#include <math.h>

constexpr int Bb  = 64;
constexpr int Tt  = 2048;
constexpr int INN = 128;
constexpr int HH  = 256;
constexpr int ROWS = Bb * Tt;   // 131072
constexpr int CH  = 64;         // pipeline chunk (rows of one batch)
constexpr int NCH = Tt / CH;    // 32 chunks
constexpr int PS  = HH + 4;     // 260: partial-buffer row stride (2-way banks)

// Inter-role progress flags (rows completed per batch). Monotonic within one
// kernel execution; re-zeroed by ih_gemm (previous kernel in stream) each run.
__device__ int g_flag0[Bb];     // producer  -> gemm
__device__ int g_flag1[Bb];     // gemm      -> consumer

// ---------------------------------------------------------------------------
// Sync helpers. CRITICAL (v7 post-mortem): an ACQUIRE atomic in the poll
// loop emits buffer_inv (full per-XCD L2 invalidate) EVERY iteration,
// destroying L2 for all co-resident roles (FETCH_SIZE +30%, phases 1400 ->
// 2300 cyc). Poll RELAXED (sc1 load, no inv); issue ONE acquire fence after
// the flag test passes. Release store alone provides the writeback (no
// extra __threadfence, which double-pays wb+inv).
// ---------------------------------------------------------------------------
__device__ __forceinline__ void wait_flag(int* flag, int want)
{
    while (__hip_atomic_load(flag, __ATOMIC_RELAXED,
                             __HIP_MEMORY_SCOPE_AGENT) < want)
        __builtin_amdgcn_s_sleep(16);
    __builtin_amdgcn_fence(__ATOMIC_ACQUIRE, "agent");   // one inv per chunk
}

__device__ __forceinline__ void release_flag(int* flag, int val)
{
    __hip_atomic_store(flag, val, __ATOMIC_RELEASE, __HIP_MEMORY_SCOPE_AGENT);
}

// ---------------------------------------------------------------------------
// xp0 GEMM: out[row][j] = sum_k x[row][k]*W[j][k] + b1[j] + b2[j], K=128.
// 256 threads, 64x256 tile, 8x8 per thread (v5-verified machinery).
// Block 0 additionally zeroes the pipeline flags for this run.
// ---------------------------------------------------------------------------
__global__ __launch_bounds__(256) void ih_gemm(const float* in, const float* W,
                                               const float* bias1, const float* bias2,
                                               float* out)
{
    __shared__ float a_lds[16][68];
    __shared__ float b_lds[16][260];

    const int tid = threadIdx.x;
    if (blockIdx.x == 0 && tid < Bb) { g_flag0[tid] = 0; g_flag1[tid] = 0; }

    const int tx  = tid & 31;
    const int ty  = tid >> 5;
    const int row0 = blockIdx.x * 64;

    float acc[8][8];
#pragma unroll
    for (int r = 0; r < 8; ++r)
#pragma unroll
        for (int c = 0; c < 8; ++c) acc[r][c] = 0.f;

    for (int k0 = 0; k0 < INN; k0 += 16) {
#pragma unroll
        for (int i = 0; i < 4; ++i) {
            int e = i * 256 + tid;
            int r = e >> 4, kk = e & 15;
            a_lds[kk][r] = in[(row0 + r) * INN + k0 + kk];
        }
#pragma unroll
        for (int i = 0; i < 16; ++i) {
            int e = i * 256 + tid;
            int j = e >> 4, kk = e & 15;
            b_lds[kk][j] = W[j * INN + k0 + kk];
        }
        __syncthreads();

#pragma unroll
        for (int kk = 0; kk < 16; ++kk) {
            float4 a0 = *(const float4*)&a_lds[kk][ty * 8];
            float4 a1 = *(const float4*)&a_lds[kk][ty * 8 + 4];
            float4 b0 = *(const float4*)&b_lds[kk][tx * 8];
            float4 b1 = *(const float4*)&b_lds[kk][tx * 8 + 4];
            float av[8] = {a0.x, a0.y, a0.z, a0.w, a1.x, a1.y, a1.z, a1.w};
            float bv[8] = {b0.x, b0.y, b0.z, b0.w, b1.x, b1.y, b1.z, b1.w};
#pragma unroll
            for (int r = 0; r < 8; ++r)
#pragma unroll
                for (int c = 0; c < 8; ++c)
                    acc[r][c] += av[r] * bv[c];
        }
        __syncthreads();
    }

    float bsum[8];
#pragma unroll
    for (int c = 0; c < 8; ++c) {
        int j = tx * 8 + c;
        bsum[c] = bias1[j] + bias2[j];
    }
#pragma unroll
    for (int r = 0; r < 8; ++r) {
        int row = row0 + ty * 8 + r;
        float4 o0 = make_float4(acc[r][0] + bsum[0], acc[r][1] + bsum[1],
                                acc[r][2] + bsum[2], acc[r][3] + bsum[3]);
        float4 o1 = make_float4(acc[r][4] + bsum[4], acc[r][5] + bsum[5],
                                acc[r][6] + bsum[6], acc[r][7] + bsum[7]);
        *(float4*)&out[row * HH + tx * 8]     = o0;
        *(float4*)&out[row * HH + tx * 8 + 4] = o1;
    }
}

// ---------------------------------------------------------------------------
// fast tanh, clamp-free: x->+inf: e=inf, rcp=0 -> 1; x->-inf: e=0 -> -1.
// ---------------------------------------------------------------------------
__device__ __forceinline__ float fast_tanh(float x)
{
    float e = __builtin_amdgcn_exp2f(x * 2.8853900817779268f);  // 2*log2(e)
    return fmaf(-2.0f, __builtin_amdgcn_rcpf(e + 1.0f), 1.0f);
}

__device__ __forceinline__ float fold16(float s)
{
    int v = __builtin_amdgcn_ds_swizzle(__float_as_int(s), 0x401F);  // xor 16
    return s + __int_as_float(v);
}

__device__ __forceinline__ float fold32(float s)
{
#if __has_builtin(__builtin_amdgcn_permlane32_swap)
    typedef unsigned uint2v __attribute__((ext_vector_type(2)));
    uint2v r = __builtin_amdgcn_permlane32_swap(__float_as_uint(s), __float_as_uint(s),
                                                false, false);
    return __uint_as_float(r[0]) + __uint_as_float(r[1]);
#else
    return s + __shfl_xor(s, 32, 64);
#endif
}

// weights load: wreg[r][c] = W[(4l + r)*HH + 16w + c]
__device__ __forceinline__ void load_wreg(const float* W, int l, int w,
                                          float (&wreg)[4][16])
{
#pragma unroll
    for (int r = 0; r < 4; ++r) {
        const float4* wp = (const float4*)&W[(size_t)(4 * l + r) * HH + 16 * w];
#pragma unroll
        for (int q = 0; q < 4; ++q) {
            float4 v = wp[q];
            wreg[r][4 * q + 0] = v.x;
            wreg[r][4 * q + 1] = v.y;
            wreg[r][4 * q + 2] = v.z;
            wreg[r][4 * q + 3] = v.w;
        }
    }
}

// MAC: partials of (W-chunk) * broadcast(xg) -> b128 write to wr
__device__ __forceinline__ void mac_partials(float xg, const float (&wreg)[4][16],
                                             float* wr)
{
    float p0 = 0.f, p1 = 0.f, p2 = 0.f, p3 = 0.f;
#pragma unroll
    for (int c = 0; c < 16; ++c) {
        float hcv = __int_as_float(__builtin_amdgcn_readlane(__float_as_int(xg), c));
        p0 = fmaf(wreg[0][c], hcv, p0);
        p1 = fmaf(wreg[1][c], hcv, p1);
        p2 = fmaf(wreg[2][c], hcv, p2);
        p3 = fmaf(wreg[3][c], hcv, p3);
    }
    *(float4*)wr = make_float4(p0, p1, p2, p3);
}

// ---------------------------------------------------------------------------
// One recurrence step (v4-verified dataflow): reads partials from rd,
// writes next-step partials to wr, commits h over xp[t] (in-place), ONE
// barrier. xg carries xp[t]; prefetches *pr into xg for the next step.
// ---------------------------------------------------------------------------
__device__ __forceinline__ void rnn_step(const float* rd, float* wr,
                                         float*& pw, const float* pr,
                                         float& xg, const float (&wreg)[4][16],
                                         bool lane_lt16)
{
    float xg2 = *pr;

    float s0 = rd[0 * PS], s1 = rd[1 * PS], s2 = rd[2 * PS], s3 = rd[3 * PS];
    float s = (s0 + s1) + (s2 + s3);
    s = fold16(s);
    s = fold32(s);

    float hv = fast_tanh(s + xg);
    if (lane_lt16) *pw = hv;

    mac_partials(hv, wreg, wr);

    __syncthreads();
    xg = xg2;
    pw += HH;
}

// ---------------------------------------------------------------------------
// Recurrence role (producer: layer 0 / consumer: layer 1), chunked.
// PROD: releases g_flag0[b] after each 64-row chunk of h written.
// !PROD: waits g_flag1[b] per chunk (relaxed poll + one acquire fence);
//        reloads xg fresh after the wait (cross-chunk prefetch discarded).
// ---------------------------------------------------------------------------
template <bool PROD>
__device__ void rnn_role(float* xpb, const float* Whh, float* sh, int b)
{
    float* pbufA = sh;
    float* pbufB = sh + 16 * PS;

    const int tid = threadIdx.x;
    const int w   = tid >> 6;
    const int l   = tid & 63;
    const int g   = l >> 4;
    const int jr  = 16 * w + (l & 15);
    const bool lane_lt16 = (l < 16);

    float wreg[4][16];
    load_wreg(Whh, l, w, wreg);

    const float* rdA = &pbufA[4 * g * PS + jr];
    const float* rdB = &pbufB[4 * g * PS + jr];
    float*       wrA = &pbufA[w * PS + 4 * l];
    float*       wrB = &pbufB[w * PS + 4 * l];

    *(float4*)wrA = make_float4(0.f, 0.f, 0.f, 0.f);   // h_{-1} = 0
    float xg = PROD ? xpb[jr] : 0.f;    // consumer: overwritten post-wait
    float* pw = xpb + jr;
    const float* pr = xpb + HH + jr;
    __syncthreads();

#pragma unroll 1
    for (int c = 0; c < NCH; ++c) {
        if (!PROD) {
            wait_flag(&g_flag1[b], (c + 1) * CH);
            xg = xpb[(size_t)c * CH * HH + jr];
        }
        const int npairs = (c == NCH - 1) ? (CH / 2 - 1) : (CH / 2);
#pragma unroll 1
        for (int p = 0; p < npairs; ++p) {
            rnn_step(rdA, wrB, pw, pr, xg, wreg, lane_lt16); pr += HH;
            rnn_step(rdB, wrA, pw, pr, xg, wreg, lane_lt16); pr += HH;
        }
        if (c == NCH - 1) {   // final pair: prefetch clamped to row Tt-1
            rnn_step(rdA, wrB, pw, pr, xg, wreg, lane_lt16);
            rnn_step(rdB, wrA, pw, pr, xg, wreg, lane_lt16);
        }
        if (PROD && tid == 0)
            release_flag(&g_flag0[b], (c + 1) * CH);
    }
}

// ---------------------------------------------------------------------------
// GEMM role (matvec formulation, v7-verified dataflow):
// xp1[r][j] = sum_k Wih1[j][k] * h1[r][k] + bias[j], row by row, in place.
// Phase p: reduce row p-1 partials (+bias, store), MAC row p partials into
// the other buffer, ONE barrier. Rows independent -> fully pipelined.
// ---------------------------------------------------------------------------
__device__ __forceinline__ void gemm_phase(const float* rd, float* wr,
                                           float*& pw, const float* pr,
                                           float& xg, const float (&wreg)[4][16],
                                           float bsc, bool lane_lt16)
{
    float xg2 = *pr;                 // prefetch row p+1

    float s0 = rd[0 * PS], s1 = rd[1 * PS], s2 = rd[2 * PS], s3 = rd[3 * PS];
    float s = (s0 + s1) + (s2 + s3);
    s = fold16(s);
    s = fold32(s);
    if (lane_lt16) *pw = s + bsc;    // commit xp1[row p-1][jr]

    mac_partials(xg, wreg, wr);      // partials for row p

    __syncthreads();
    xg = xg2;
    pw += HH;
}

__device__ void gemm_role(float* ws, const float* W,
                          const float* b1, const float* b2, float* sh, int b)
{
    float* pbufA = sh;
    float* pbufB = sh + 16 * PS;

    const int tid = threadIdx.x;
    const int w   = tid >> 6;
    const int l   = tid & 63;
    const int g   = l >> 4;
    const int jr  = 16 * w + (l & 15);
    const bool lane_lt16 = (l < 16);

    float wreg[4][16];
    load_wreg(W, l, w, wreg);
    const float bsc = b1[jr] + b2[jr];

    const float* rdA = &pbufA[4 * g * PS + jr];
    const float* rdB = &pbufB[4 * g * PS + jr];
    float*       wrA = &pbufA[w * PS + 4 * l];
    float*       wrB = &pbufB[w * PS + 4 * l];

#pragma unroll 1
    for (int c = 0; c < NCH; ++c) {
        wait_flag(&g_flag0[b], (c + 1) * CH);

        float* Ab = ws + ((size_t)b * Tt + (size_t)c * CH) * HH;

        // phase 0 (peeled): MAC row 0, no reduce/store
        float xg  = Ab[jr];              // row 0, fresh post-wait
        float xg2 = Ab[HH + jr];         // prefetch row 1
        mac_partials(xg, wreg, wrB);
        __syncthreads();
        xg = xg2;

        float* pw = Ab + jr;             // store ptr, starts at row 0
        const float* pr = Ab + 2 * HH + jr;   // prefetch ptr (row 2)

        // phases 1..62 (31 pairs): odd reads B writes A, even reads A writes B
#pragma unroll 1
        for (int p = 0; p < 31; ++p) {
            gemm_phase(rdB, wrA, pw, pr, xg, wreg, bsc, lane_lt16); pr += HH;
            gemm_phase(rdA, wrB, pw, pr, xg, wreg, bsc, lane_lt16); pr += HH;
        }
        // phase 63: prefetch clamped to row 63 (value discarded at chunk end)
        gemm_phase(rdB, wrA, pw, pr - HH, xg, wreg, bsc, lane_lt16);

        // tail phase 64: reduce row 63 only
        {
            float s0 = rdA[0 * PS], s1 = rdA[1 * PS];
            float s2 = rdA[2 * PS], s3 = rdA[3 * PS];
            float s = (s0 + s1) + (s2 + s3);
            s = fold16(s);
            s = fold32(s);
            if (lane_lt16) *pw = s + bsc;
            __syncthreads();
        }

        if (tid == 0)
            release_flag(&g_flag1[b], (c + 1) * CH);
    }
}

// ---------------------------------------------------------------------------
// Pipelined fused kernel: blocks 0..63 producer (layer-0 recurrence),
// 64..127 gemm (xp1 matvecs), 128..191 consumer (layer-1 recurrence).
// 192 blocks <= 256 CUs, wait graph is a DAG => no deadlock.
// ---------------------------------------------------------------------------
__global__ __launch_bounds__(1024, 4) void pipeline_kernel(
        float* ws, const float* Whh0, const float* Wih1,
        const float* bih1, const float* bhh1, const float* Whh1)
{
    __shared__ __attribute__((aligned(16))) float sh[2 * 16 * PS];  // 33280 B

    const int role = blockIdx.x >> 6;
    const int b    = blockIdx.x & 63;

    if (role == 0)
        rnn_role<true>(ws + (size_t)b * Tt * HH, Whh0, sh, b);
    else if (role == 1)
        gemm_role(ws, Wih1, bih1, bhh1, sh, b);
    else
        rnn_role<false>(ws + (size_t)b * Tt * HH, Whh1, sh, b);
}

// ---------------------------------------------------------------------------
// FC: out[b] = dot(h2[b][T-1][:], W_fc) + b_fc.  One wave per batch.
// ---------------------------------------------------------------------------
__global__ __launch_bounds__(64) void fc_kernel(const float* h2, const float* Wfc,
                                                const float* bfc, float* out)
{
    const int b = blockIdx.x;
    const int l = threadIdx.x;
    const float* hrow = h2 + ((size_t)b * Tt + (Tt - 1)) * HH;
    float4 hv = *(const float4*)&hrow[4 * l];
    float4 wv = *(const float4*)&Wfc[4 * l];
    float p = hv.x * wv.x + hv.y * wv.y + hv.z * wv.z + hv.w * wv.w;
#pragma unroll
    for (int off = 32; off > 0; off >>= 1) p += __shfl_down(p, off, 64);
    if (l == 0) out[b] = p + bfc[0];
}

// ---------------------------------------------------------------------------
extern "C" void kernel_launch(void* const* d_in, const int* in_sizes, int n_in,
                              void* d_out, int out_size, void* d_ws, size_t ws_size,
                              hipStream_t stream)
{
    const float* x     = (const float*)d_in[0];
    const float* W_ih0 = (const float*)d_in[1];
    const float* W_hh0 = (const float*)d_in[2];
    const float* b_ih0 = (const float*)d_in[3];
    const float* b_hh0 = (const float*)d_in[4];
    const float* W_ih1 = (const float*)d_in[5];
    const float* W_hh1 = (const float*)d_in[6];
    const float* b_ih1 = (const float*)d_in[7];
    const float* b_hh1 = (const float*)d_in[8];
    const float* W_fc  = (const float*)d_in[9];
    const float* b_fc  = (const float*)d_in[10];
    float* ws  = (float*)d_ws;                 // B*T*H floats (128 MiB)
    float* out = (float*)d_out;

    // 1) xp0 = x @ W_ih0^T + b_ih0 + b_hh0  (+ zero pipeline flags)
    ih_gemm<<<ROWS / 64, 256, 0, stream>>>(x, W_ih0, b_ih0, b_hh0, ws);
    // 2) fused pipeline: L0 recurrence -> chunked xp1 matvec -> L1 recurrence,
    //    all in-place in ws; ws ends as the h2 sequence.
    pipeline_kernel<<<192, 1024, 0, stream>>>(ws, W_hh0, W_ih1, b_ih1, b_hh1, W_hh1);
    // 3) out = h2[:, T-1, :] @ W_fc^T + b_fc
    fc_kernel<<<Bb, 64, 0, stream>>>(ws, W_fc, b_fc, out);
}

// Round 8
// 1859.700 us; speedup vs baseline: 2.2561x; 1.0069x over previous
//
#include <hip/hip_runtime.h>
#include <math.h>

constexpr int Bb  = 64;
constexpr int Tt  = 2048;
constexpr int INN = 128;
constexpr int HH  = 256;
constexpr int ROWS = Bb * Tt;   // 131072
constexpr int CH  = 64;         // pipeline chunk (rows of one batch)
constexpr int NCH = Tt / CH;    // 32 chunks
constexpr int PS  = HH + 4;     // 260: partial-buffer row stride (2-way banks)

// Inter-role progress flags (rows completed per batch). Monotonic within one
// kernel execution; re-zeroed by ih_gemm (previous kernel in stream) each run.
__device__ int g_flag0[Bb];     // producer  -> gemm
__device__ int g_flag1[Bb];     // gemm      -> consumer

// ---------------------------------------------------------------------------
// Sync helpers.
// v7 lesson: ACQUIRE in the poll loop = buffer_inv per iteration = L2
//   wrecked for all co-resident roles.
// v8 lesson: RELAXED AGENT poll can be served by the waiter's own (stale,
//   non-coherent) XCD L2 -> handoffs wait for "rescue" invalidates from
//   other blocks, quantizing the pipeline (~19 us/chunk of dead time).
// Fix: poll at SYSTEM scope (sc0+sc1 load, bypasses L2, reads MALL every
// time, no inv), then ONE agent acquire fence after the flag test passes.
// Release store (agent scope) writes through to MALL after wbl2.
// ---------------------------------------------------------------------------
__device__ __forceinline__ void wait_flag(int* flag, int want)
{
    while (__hip_atomic_load(flag, __ATOMIC_RELAXED,
                             __HIP_MEMORY_SCOPE_SYSTEM) < want)
        __builtin_amdgcn_s_sleep(8);
    __builtin_amdgcn_fence(__ATOMIC_ACQUIRE, "agent");   // one inv per chunk
}

__device__ __forceinline__ void release_flag(int* flag, int val)
{
    __hip_atomic_store(flag, val, __ATOMIC_RELEASE, __HIP_MEMORY_SCOPE_AGENT);
}

// In-chunk barrier: LDS-only ordering. __syncthreads() drains vmcnt(0) too,
// which exposes the global h-store ack (~300-500 cyc to L2/MALL) on EVERY
// step's serial chain. Within a chunk, all global xp accesses are
// wave-private columns (jr in [16w,16w+16) for wave w) -> no cross-wave
// global hazard; only the LDS partial exchange needs the barrier. Full
// __syncthreads() is used ONLY on the last step before a flag release.
__device__ __forceinline__ void lds_barrier()
{
    asm volatile("s_waitcnt lgkmcnt(0)" ::: "memory");
    __builtin_amdgcn_s_barrier();
}

// ---------------------------------------------------------------------------
// xp0 GEMM: out[row][j] = sum_k x[row][k]*W[j][k] + b1[j] + b2[j], K=128.
// 256 threads, 64x256 tile, 8x8 per thread (v5-verified machinery).
// Block 0 additionally zeroes the pipeline flags for this run.
// ---------------------------------------------------------------------------
__global__ __launch_bounds__(256) void ih_gemm(const float* in, const float* W,
                                               const float* bias1, const float* bias2,
                                               float* out)
{
    __shared__ float a_lds[16][68];
    __shared__ float b_lds[16][260];

    const int tid = threadIdx.x;
    if (blockIdx.x == 0 && tid < Bb) { g_flag0[tid] = 0; g_flag1[tid] = 0; }

    const int tx  = tid & 31;
    const int ty  = tid >> 5;
    const int row0 = blockIdx.x * 64;

    float acc[8][8];
#pragma unroll
    for (int r = 0; r < 8; ++r)
#pragma unroll
        for (int c = 0; c < 8; ++c) acc[r][c] = 0.f;

    for (int k0 = 0; k0 < INN; k0 += 16) {
#pragma unroll
        for (int i = 0; i < 4; ++i) {
            int e = i * 256 + tid;
            int r = e >> 4, kk = e & 15;
            a_lds[kk][r] = in[(row0 + r) * INN + k0 + kk];
        }
#pragma unroll
        for (int i = 0; i < 16; ++i) {
            int e = i * 256 + tid;
            int j = e >> 4, kk = e & 15;
            b_lds[kk][j] = W[j * INN + k0 + kk];
        }
        __syncthreads();

#pragma unroll
        for (int kk = 0; kk < 16; ++kk) {
            float4 a0 = *(const float4*)&a_lds[kk][ty * 8];
            float4 a1 = *(const float4*)&a_lds[kk][ty * 8 + 4];
            float4 b0 = *(const float4*)&b_lds[kk][tx * 8];
            float4 b1 = *(const float4*)&b_lds[kk][tx * 8 + 4];
            float av[8] = {a0.x, a0.y, a0.z, a0.w, a1.x, a1.y, a1.z, a1.w};
            float bv[8] = {b0.x, b0.y, b0.z, b0.w, b1.x, b1.y, b1.z, b1.w};
#pragma unroll
            for (int r = 0; r < 8; ++r)
#pragma unroll
                for (int c = 0; c < 8; ++c)
                    acc[r][c] += av[r] * bv[c];
        }
        __syncthreads();
    }

    float bsum[8];
#pragma unroll
    for (int c = 0; c < 8; ++c) {
        int j = tx * 8 + c;
        bsum[c] = bias1[j] + bias2[j];
    }
#pragma unroll
    for (int r = 0; r < 8; ++r) {
        int row = row0 + ty * 8 + r;
        float4 o0 = make_float4(acc[r][0] + bsum[0], acc[r][1] + bsum[1],
                                acc[r][2] + bsum[2], acc[r][3] + bsum[3]);
        float4 o1 = make_float4(acc[r][4] + bsum[4], acc[r][5] + bsum[5],
                                acc[r][6] + bsum[6], acc[r][7] + bsum[7]);
        *(float4*)&out[row * HH + tx * 8]     = o0;
        *(float4*)&out[row * HH + tx * 8 + 4] = o1;
    }
}

// ---------------------------------------------------------------------------
// fast tanh, clamp-free: x->+inf: e=inf, rcp=0 -> 1; x->-inf: e=0 -> -1.
// ---------------------------------------------------------------------------
__device__ __forceinline__ float fast_tanh(float x)
{
    float e = __builtin_amdgcn_exp2f(x * 2.8853900817779268f);  // 2*log2(e)
    return fmaf(-2.0f, __builtin_amdgcn_rcpf(e + 1.0f), 1.0f);
}

__device__ __forceinline__ float fold16(float s)
{
    int v = __builtin_amdgcn_ds_swizzle(__float_as_int(s), 0x401F);  // xor 16
    return s + __int_as_float(v);
}

__device__ __forceinline__ float fold32(float s)
{
#if __has_builtin(__builtin_amdgcn_permlane32_swap)
    typedef unsigned uint2v __attribute__((ext_vector_type(2)));
    uint2v r = __builtin_amdgcn_permlane32_swap(__float_as_uint(s), __float_as_uint(s),
                                                false, false);
    return __uint_as_float(r[0]) + __uint_as_float(r[1]);
#else
    return s + __shfl_xor(s, 32, 64);
#endif
}

// weights load: wreg[r][c] = W[(4l + r)*HH + 16w + c]
__device__ __forceinline__ void load_wreg(const float* W, int l, int w,
                                          float (&wreg)[4][16])
{
#pragma unroll
    for (int r = 0; r < 4; ++r) {
        const float4* wp = (const float4*)&W[(size_t)(4 * l + r) * HH + 16 * w];
#pragma unroll
        for (int q = 0; q < 4; ++q) {
            float4 v = wp[q];
            wreg[r][4 * q + 0] = v.x;
            wreg[r][4 * q + 1] = v.y;
            wreg[r][4 * q + 2] = v.z;
            wreg[r][4 * q + 3] = v.w;
        }
    }
}

// MAC: partials of (W-chunk) * broadcast(xg) -> b128 write to wr
__device__ __forceinline__ void mac_partials(float xg, const float (&wreg)[4][16],
                                             float* wr)
{
    float p0 = 0.f, p1 = 0.f, p2 = 0.f, p3 = 0.f;
#pragma unroll
    for (int c = 0; c < 16; ++c) {
        float hcv = __int_as_float(__builtin_amdgcn_readlane(__float_as_int(xg), c));
        p0 = fmaf(wreg[0][c], hcv, p0);
        p1 = fmaf(wreg[1][c], hcv, p1);
        p2 = fmaf(wreg[2][c], hcv, p2);
        p3 = fmaf(wreg[3][c], hcv, p3);
    }
    *(float4*)wr = make_float4(p0, p1, p2, p3);
}

// ---------------------------------------------------------------------------
// One recurrence step (v4-verified dataflow): reads partials from rd,
// writes next-step partials to wr, commits h over xp[t] (in-place), ONE
// barrier. FS: full __syncthreads (drains vmcnt; used only as the last step
// before a flag release) vs lds_barrier (lgkmcnt-only).
// ---------------------------------------------------------------------------
template <bool FS>
__device__ __forceinline__ void rnn_step(const float* rd, float* wr,
                                         float*& pw, const float* pr,
                                         float& xg, const float (&wreg)[4][16],
                                         bool lane_lt16)
{
    float xg2 = *pr;

    float s0 = rd[0 * PS], s1 = rd[1 * PS], s2 = rd[2 * PS], s3 = rd[3 * PS];
    float s = (s0 + s1) + (s2 + s3);
    s = fold16(s);
    s = fold32(s);

    float hv = fast_tanh(s + xg);
    if (lane_lt16) *pw = hv;

    mac_partials(hv, wreg, wr);

    if (FS) __syncthreads(); else lds_barrier();
    xg = xg2;
    pw += HH;
}

// ---------------------------------------------------------------------------
// Recurrence role (producer: layer 0 / consumer: layer 1), chunked.
// PROD: releases g_flag0[b] after each 64-row chunk (last step of the chunk
//       is a full __syncthreads so every wave's h-stores are drained first).
// !PROD: waits g_flag1[b] per chunk; reloads xg fresh after the wait
//       (cross-chunk prefetch may be stale and is discarded). All-raw
//       barriers (its stores are consumed only after kernel end).
// ---------------------------------------------------------------------------
template <bool PROD>
__device__ void rnn_role(float* xpb, const float* Whh, float* sh, int b)
{
    float* pbufA = sh;
    float* pbufB = sh + 16 * PS;

    const int tid = threadIdx.x;
    const int w   = tid >> 6;
    const int l   = tid & 63;
    const int g   = l >> 4;
    const int jr  = 16 * w + (l & 15);
    const bool lane_lt16 = (l < 16);

    float wreg[4][16];
    load_wreg(Whh, l, w, wreg);

    const float* rdA = &pbufA[4 * g * PS + jr];
    const float* rdB = &pbufB[4 * g * PS + jr];
    float*       wrA = &pbufA[w * PS + 4 * l];
    float*       wrB = &pbufB[w * PS + 4 * l];

    *(float4*)wrA = make_float4(0.f, 0.f, 0.f, 0.f);   // h_{-1} = 0
    float xg = PROD ? xpb[jr] : 0.f;    // consumer: overwritten post-wait
    float* pw = xpb + jr;
    const float* pr = xpb + HH + jr;
    __syncthreads();

#pragma unroll 1
    for (int c = 0; c < NCH; ++c) {
        if (!PROD) {
            wait_flag(&g_flag1[b], (c + 1) * CH);
            xg = xpb[(size_t)c * CH * HH + jr];
        }
        // 31 full-rate pairs (raw barriers)
#pragma unroll 1
        for (int p = 0; p < CH / 2 - 1; ++p) {
            rnn_step<false>(rdA, wrB, pw, pr, xg, wreg, lane_lt16); pr += HH;
            rnn_step<false>(rdB, wrA, pw, pr, xg, wreg, lane_lt16); pr += HH;
        }
        // final pair of the chunk: second step drains vmcnt if PROD.
        if (c < NCH - 1) {
            rnn_step<false>(rdA, wrB, pw, pr, xg, wreg, lane_lt16); pr += HH;
            rnn_step<PROD>(rdB, wrA, pw, pr, xg, wreg, lane_lt16);  pr += HH;
        } else {   // last chunk: prefetch clamped to row Tt-1 (discarded)
            rnn_step<false>(rdA, wrB, pw, pr, xg, wreg, lane_lt16);
            rnn_step<PROD>(rdB, wrA, pw, pr, xg, wreg, lane_lt16);
        }
        if (PROD && tid == 0)
            release_flag(&g_flag0[b], (c + 1) * CH);
    }
}

// ---------------------------------------------------------------------------
// GEMM role (matvec formulation, v7-verified dataflow):
// xp1[r][j] = sum_k Wih1[j][k] * h1[r][k] + bias[j], row by row, in place.
// Phase p: reduce row p-1 partials (+bias, store), MAC row p partials into
// the other buffer, ONE raw barrier. Tail phase full-syncs before release.
// ---------------------------------------------------------------------------
__device__ __forceinline__ void gemm_phase(const float* rd, float* wr,
                                           float*& pw, const float* pr,
                                           float& xg, const float (&wreg)[4][16],
                                           float bsc, bool lane_lt16)
{
    float xg2 = *pr;                 // prefetch row p+1

    float s0 = rd[0 * PS], s1 = rd[1 * PS], s2 = rd[2 * PS], s3 = rd[3 * PS];
    float s = (s0 + s1) + (s2 + s3);
    s = fold16(s);
    s = fold32(s);
    if (lane_lt16) *pw = s + bsc;    // commit xp1[row p-1][jr]

    mac_partials(xg, wreg, wr);      // partials for row p

    lds_barrier();
    xg = xg2;
    pw += HH;
}

__device__ void gemm_role(float* ws, const float* W,
                          const float* b1, const float* b2, float* sh, int b)
{
    float* pbufA = sh;
    float* pbufB = sh + 16 * PS;

    const int tid = threadIdx.x;
    const int w   = tid >> 6;
    const int l   = tid & 63;
    const int g   = l >> 4;
    const int jr  = 16 * w + (l & 15);
    const bool lane_lt16 = (l < 16);

    float wreg[4][16];
    load_wreg(W, l, w, wreg);
    const float bsc = b1[jr] + b2[jr];

    const float* rdA = &pbufA[4 * g * PS + jr];
    const float* rdB = &pbufB[4 * g * PS + jr];
    float*       wrA = &pbufA[w * PS + 4 * l];
    float*       wrB = &pbufB[w * PS + 4 * l];

#pragma unroll 1
    for (int c = 0; c < NCH; ++c) {
        wait_flag(&g_flag0[b], (c + 1) * CH);

        float* Ab = ws + ((size_t)b * Tt + (size_t)c * CH) * HH;

        // phase 0 (peeled): MAC row 0, no reduce/store
        float xg  = Ab[jr];              // row 0, fresh post-wait
        float xg2 = Ab[HH + jr];         // prefetch row 1
        mac_partials(xg, wreg, wrB);
        lds_barrier();
        xg = xg2;

        float* pw = Ab + jr;             // store ptr, starts at row 0
        const float* pr = Ab + 2 * HH + jr;   // prefetch ptr (row 2)

        // phases 1..62 (31 pairs): odd reads B writes A, even reads A writes B
#pragma unroll 1
        for (int p = 0; p < 31; ++p) {
            gemm_phase(rdB, wrA, pw, pr, xg, wreg, bsc, lane_lt16); pr += HH;
            gemm_phase(rdA, wrB, pw, pr, xg, wreg, bsc, lane_lt16); pr += HH;
        }
        // phase 63: prefetch clamped to row 63 (value discarded at chunk end)
        gemm_phase(rdB, wrA, pw, pr - HH, xg, wreg, bsc, lane_lt16);

        // tail phase 64: reduce row 63 only; FULL sync drains all stores
        {
            float s0 = rdA[0 * PS], s1 = rdA[1 * PS];
            float s2 = rdA[2 * PS], s3 = rdA[3 * PS];
            float s = (s0 + s1) + (s2 + s3);
            s = fold16(s);
            s = fold32(s);
            if (lane_lt16) *pw = s + bsc;
            __syncthreads();
        }

        if (tid == 0)
            release_flag(&g_flag1[b], (c + 1) * CH);
    }
}

// ---------------------------------------------------------------------------
// Pipelined fused kernel: blocks 0..63 producer (layer-0 recurrence),
// 64..127 gemm (xp1 matvecs), 128..191 consumer (layer-1 recurrence).
// 192 blocks <= 256 CUs, wait graph is a DAG => no deadlock.
// ---------------------------------------------------------------------------
__global__ __launch_bounds__(1024, 4) void pipeline_kernel(
        float* ws, const float* Whh0, const float* Wih1,
        const float* bih1, const float* bhh1, const float* Whh1)
{
    __shared__ __attribute__((aligned(16))) float sh[2 * 16 * PS];  // 33280 B

    const int role = blockIdx.x >> 6;
    const int b    = blockIdx.x & 63;

    if (role == 0)
        rnn_role<true>(ws + (size_t)b * Tt * HH, Whh0, sh, b);
    else if (role == 1)
        gemm_role(ws, Wih1, bih1, bhh1, sh, b);
    else
        rnn_role<false>(ws + (size_t)b * Tt * HH, Whh1, sh, b);
}

// ---------------------------------------------------------------------------
// FC: out[b] = dot(h2[b][T-1][:], W_fc) + b_fc.  One wave per batch.
// ---------------------------------------------------------------------------
__global__ __launch_bounds__(64) void fc_kernel(const float* h2, const float* Wfc,
                                                const float* bfc, float* out)
{
    const int b = blockIdx.x;
    const int l = threadIdx.x;
    const float* hrow = h2 + ((size_t)b * Tt + (Tt - 1)) * HH;
    float4 hv = *(const float4*)&hrow[4 * l];
    float4 wv = *(const float4*)&Wfc[4 * l];
    float p = hv.x * wv.x + hv.y * wv.y + hv.z * wv.z + hv.w * wv.w;
#pragma unroll
    for (int off = 32; off > 0; off >>= 1) p += __shfl_down(p, off, 64);
    if (l == 0) out[b] = p + bfc[0];
}

// ---------------------------------------------------------------------------
extern "C" void kernel_launch(void* const* d_in, const int* in_sizes, int n_in,
                              void* d_out, int out_size, void* d_ws, size_t ws_size,
                              hipStream_t stream)
{
    const float* x     = (const float*)d_in[0];
    const float* W_ih0 = (const float*)d_in[1];
    const float* W_hh0 = (const float*)d_in[2];
    const float* b_ih0 = (const float*)d_in[3];
    const float* b_hh0 = (const float*)d_in[4];
    const float* W_ih1 = (const float*)d_in[5];
    const float* W_hh1 = (const float*)d_in[6];
    const float* b_ih1 = (const float*)d_in[7];
    const float* b_hh1 = (const float*)d_in[8];
    const float* W_fc  = (const float*)d_in[9];
    const float* b_fc  = (const float*)d_in[10];
    float* ws  = (float*)d_ws;                 // B*T*H floats (128 MiB)
    float* out = (float*)d_out;

    // 1) xp0 = x @ W_ih0^T + b_ih0 + b_hh0  (+ zero pipeline flags)
    ih_gemm<<<ROWS / 64, 256, 0, stream>>>(x, W_ih0, b_ih0, b_hh0, ws);
    // 2) fused pipeline: L0 recurrence -> chunked xp1 matvec -> L1 recurrence,
    //    all in-place in ws; ws ends as the h2 sequence.
    pipeline_kernel<<<192, 1024, 0, stream>>>(ws, W_hh0, W_ih1, b_ih1, b_hh1, W_hh1);
    // 3) out = h2[:, T-1, :] @ W_fc^T + b_fc
    fc_kernel<<<Bb, 64, 0, stream>>>(ws, W_fc, b_fc, out);
}

// Round 9
// 1509.338 us; speedup vs baseline: 2.7798x; 1.2321x over previous
//
#include <hip/hip_runtime.h>
#include <math.h>

constexpr int Bb  = 64;
constexpr int Tt  = 2048;
constexpr int INN = 128;
constexpr int HH  = 256;
constexpr int ROWS = Bb * Tt;   // 131072
constexpr int CH  = 64;         // pipeline chunk (rows of one batch)
constexpr int NCH = Tt / CH;    // 32 chunks
constexpr int PS  = HH + 4;     // 260: partial-buffer row stride (2-way banks)

// Inter-role progress flags (rows completed per batch). Monotonic within one
// kernel execution; re-zeroed by ih_gemm (previous kernel in stream) each run.
__device__ int g_flag0[Bb];     // producer  -> gemm (rows of h1 done)
__device__ int g_flag1[Bb];     // gemm half 0 -> consumer (its rows done)
__device__ int g_flag1b[Bb];    // gemm half 1 -> consumer

// ---------------------------------------------------------------------------
// Sync fabric (v9-verified, unchanged): SYSTEM-scope relaxed poll (no
// per-iteration buffer_inv), ONE agent acquire fence after success; agent
// release store; lgkmcnt-only barrier in-chunk, full __syncthreads (vmcnt
// drain) only on the last step before a flag release.
// ---------------------------------------------------------------------------
__device__ __forceinline__ void wait_flag(int* flag, int want)
{
    while (__hip_atomic_load(flag, __ATOMIC_RELAXED,
                             __HIP_MEMORY_SCOPE_SYSTEM) < want)
        __builtin_amdgcn_s_sleep(8);
    __builtin_amdgcn_fence(__ATOMIC_ACQUIRE, "agent");
}

__device__ __forceinline__ void wait_flag2(int* fa, int* fb, int want)
{
    for (;;) {
        int a = __hip_atomic_load(fa, __ATOMIC_RELAXED, __HIP_MEMORY_SCOPE_SYSTEM);
        int c = __hip_atomic_load(fb, __ATOMIC_RELAXED, __HIP_MEMORY_SCOPE_SYSTEM);
        if (a >= want && c >= want) break;
        __builtin_amdgcn_s_sleep(8);
    }
    __builtin_amdgcn_fence(__ATOMIC_ACQUIRE, "agent");
}

__device__ __forceinline__ void release_flag(int* flag, int val)
{
    __hip_atomic_store(flag, val, __ATOMIC_RELEASE, __HIP_MEMORY_SCOPE_AGENT);
}

__device__ __forceinline__ void lds_barrier()
{
    asm volatile("s_waitcnt lgkmcnt(0)" ::: "memory");
    __builtin_amdgcn_s_barrier();
}

// ---------------------------------------------------------------------------
// xp0 GEMM: out[row][j] = sum_k x[row][k]*W[j][k] + b1[j] + b2[j], K=128.
// 256 threads, 64x256 tile, 8x8 per thread (v5-verified machinery).
// Block 0 additionally zeroes the pipeline flags for this run.
// ---------------------------------------------------------------------------
__global__ __launch_bounds__(256) void ih_gemm(const float* in, const float* W,
                                               const float* bias1, const float* bias2,
                                               float* out)
{
    __shared__ float a_lds[16][68];
    __shared__ float b_lds[16][260];

    const int tid = threadIdx.x;
    if (blockIdx.x == 0 && tid < Bb) {
        g_flag0[tid] = 0; g_flag1[tid] = 0; g_flag1b[tid] = 0;
    }

    const int tx  = tid & 31;
    const int ty  = tid >> 5;
    const int row0 = blockIdx.x * 64;

    float acc[8][8];
#pragma unroll
    for (int r = 0; r < 8; ++r)
#pragma unroll
        for (int c = 0; c < 8; ++c) acc[r][c] = 0.f;

    for (int k0 = 0; k0 < INN; k0 += 16) {
#pragma unroll
        for (int i = 0; i < 4; ++i) {
            int e = i * 256 + tid;
            int r = e >> 4, kk = e & 15;
            a_lds[kk][r] = in[(row0 + r) * INN + k0 + kk];
        }
#pragma unroll
        for (int i = 0; i < 16; ++i) {
            int e = i * 256 + tid;
            int j = e >> 4, kk = e & 15;
            b_lds[kk][j] = W[j * INN + k0 + kk];
        }
        __syncthreads();

#pragma unroll
        for (int kk = 0; kk < 16; ++kk) {
            float4 a0 = *(const float4*)&a_lds[kk][ty * 8];
            float4 a1 = *(const float4*)&a_lds[kk][ty * 8 + 4];
            float4 b0 = *(const float4*)&b_lds[kk][tx * 8];
            float4 b1 = *(const float4*)&b_lds[kk][tx * 8 + 4];
            float av[8] = {a0.x, a0.y, a0.z, a0.w, a1.x, a1.y, a1.z, a1.w};
            float bv[8] = {b0.x, b0.y, b0.z, b0.w, b1.x, b1.y, b1.z, b1.w};
#pragma unroll
            for (int r = 0; r < 8; ++r)
#pragma unroll
                for (int c = 0; c < 8; ++c)
                    acc[r][c] += av[r] * bv[c];
        }
        __syncthreads();
    }

    float bsum[8];
#pragma unroll
    for (int c = 0; c < 8; ++c) {
        int j = tx * 8 + c;
        bsum[c] = bias1[j] + bias2[j];
    }
#pragma unroll
    for (int r = 0; r < 8; ++r) {
        int row = row0 + ty * 8 + r;
        float4 o0 = make_float4(acc[r][0] + bsum[0], acc[r][1] + bsum[1],
                                acc[r][2] + bsum[2], acc[r][3] + bsum[3]);
        float4 o1 = make_float4(acc[r][4] + bsum[4], acc[r][5] + bsum[5],
                                acc[r][6] + bsum[6], acc[r][7] + bsum[7]);
        *(float4*)&out[row * HH + tx * 8]     = o0;
        *(float4*)&out[row * HH + tx * 8 + 4] = o1;
    }
}

// ---------------------------------------------------------------------------
// fast tanh, clamp-free: x->+inf: e=inf, rcp=0 -> 1; x->-inf: e=0 -> -1.
// ---------------------------------------------------------------------------
__device__ __forceinline__ float fast_tanh(float x)
{
    float e = __builtin_amdgcn_exp2f(x * 2.8853900817779268f);  // 2*log2(e)
    return fmaf(-2.0f, __builtin_amdgcn_rcpf(e + 1.0f), 1.0f);
}

// fold across lane xor-32: both lanes end with the full sum.
__device__ __forceinline__ float fold32(float s)
{
#if __has_builtin(__builtin_amdgcn_permlane32_swap)
    typedef unsigned uint2v __attribute__((ext_vector_type(2)));
    uint2v r = __builtin_amdgcn_permlane32_swap(__float_as_uint(s), __float_as_uint(s),
                                                false, false);
    return __uint_as_float(r[0]) + __uint_as_float(r[1]);
#else
    return s + __shfl_xor(s, 32, 64);
#endif
}

// ---------------------------------------------------------------------------
// 8-wave layout (512 threads):
//   wave w (0..7) owns k-chunk [32w, 32w+32); lane l owns outputs 4l..4l+3.
//   wreg[r][c] = W[(4l+r)*HH + 32w + c]   (128 VGPRs, stationary)
//   partial write: pbuf[w*PS + 4l], float4.
//   reduce: output jr = 32w + (l&31); half hf = l>>5 sums sets 4hf..4hf+3
//     (4 b32 reads, audited exactly 2-way bank alias = free), then ONE
//     fold32 completes the 8-set sum on both halves.
//   h store / xg load: column jr (lanes l and l+32 share jr; l<32 stores).
//   readlane broadcast: lane c (c<32) holds value for k-index 32w+c.
// ---------------------------------------------------------------------------
__device__ __forceinline__ void load_wreg(const float* W, int l, int w,
                                          float (&wreg)[4][32])
{
#pragma unroll
    for (int r = 0; r < 4; ++r) {
        const float4* wp = (const float4*)&W[(size_t)(4 * l + r) * HH + 32 * w];
#pragma unroll
        for (int q = 0; q < 8; ++q) {
            float4 v = wp[q];
            wreg[r][4 * q + 0] = v.x;
            wreg[r][4 * q + 1] = v.y;
            wreg[r][4 * q + 2] = v.z;
            wreg[r][4 * q + 3] = v.w;
        }
    }
}

__device__ __forceinline__ void mac_partials(float hv, const float (&wreg)[4][32],
                                             float* wr)
{
    float p0 = 0.f, p1 = 0.f, p2 = 0.f, p3 = 0.f;
#pragma unroll
    for (int c = 0; c < 32; ++c) {
        float hcv = __int_as_float(__builtin_amdgcn_readlane(__float_as_int(hv), c));
        p0 = fmaf(wreg[0][c], hcv, p0);
        p1 = fmaf(wreg[1][c], hcv, p1);
        p2 = fmaf(wreg[2][c], hcv, p2);
        p3 = fmaf(wreg[3][c], hcv, p3);
    }
    *(float4*)wr = make_float4(p0, p1, p2, p3);
}

// One recurrence step: reduce partials of h_{t-1}, tanh, commit h over
// xp[t], MAC partials of h_t into the other buffer, one barrier.
template <bool FS>
__device__ __forceinline__ void rnn_step(const float* rd, float* wr,
                                         float*& pw, const float* pr,
                                         float& xg, const float (&wreg)[4][32],
                                         bool lane_lt32)
{
    float xg2 = *pr;

    float s0 = rd[0 * PS], s1 = rd[1 * PS], s2 = rd[2 * PS], s3 = rd[3 * PS];
    float s = (s0 + s1) + (s2 + s3);
    s = fold32(s);

    float hv = fast_tanh(s + xg);
    if (lane_lt32) *pw = hv;

    mac_partials(hv, wreg, wr);

    if (FS) __syncthreads(); else lds_barrier();
    xg = xg2;
    pw += HH;
}

// ---------------------------------------------------------------------------
// Recurrence role (producer: layer 0 / consumer: layer 1), chunked.
// ---------------------------------------------------------------------------
template <bool PROD>
__device__ void rnn_role(float* xpb, const float* Whh, float* sh, int b)
{
    float* pbufA = sh;
    float* pbufB = sh + 8 * PS;

    const int tid = threadIdx.x;
    const int w   = tid >> 6;            // 0..7
    const int l   = tid & 63;
    const int hf  = l >> 5;              // half: which 4 partial sets
    const int jr  = 32 * w + (l & 31);   // output column this lane finishes
    const bool lane_lt32 = (l < 32);

    float wreg[4][32];
    load_wreg(Whh, l, w, wreg);

    const float* rdA = &pbufA[4 * hf * PS + jr];
    const float* rdB = &pbufB[4 * hf * PS + jr];
    float*       wrA = &pbufA[w * PS + 4 * l];
    float*       wrB = &pbufB[w * PS + 4 * l];

    *(float4*)wrA = make_float4(0.f, 0.f, 0.f, 0.f);   // h_{-1} = 0
    float xg = PROD ? xpb[jr] : 0.f;    // consumer: overwritten post-wait
    float* pw = xpb + jr;
    const float* pr = xpb + HH + jr;
    __syncthreads();

#pragma unroll 1
    for (int c = 0; c < NCH; ++c) {
        if (!PROD) {
            wait_flag2(&g_flag1[b], &g_flag1b[b], (c + 1) * (CH / 2));
            xg = xpb[(size_t)c * CH * HH + jr];
        }
#pragma unroll 1
        for (int p = 0; p < CH / 2 - 1; ++p) {
            rnn_step<false>(rdA, wrB, pw, pr, xg, wreg, lane_lt32); pr += HH;
            rnn_step<false>(rdB, wrA, pw, pr, xg, wreg, lane_lt32); pr += HH;
        }
        if (c < NCH - 1) {
            rnn_step<false>(rdA, wrB, pw, pr, xg, wreg, lane_lt32); pr += HH;
            rnn_step<PROD>(rdB, wrA, pw, pr, xg, wreg, lane_lt32);  pr += HH;
        } else {   // last chunk: prefetch clamped to row Tt-1 (discarded)
            rnn_step<false>(rdA, wrB, pw, pr, xg, wreg, lane_lt32);
            rnn_step<PROD>(rdB, wrA, pw, pr, xg, wreg, lane_lt32);
        }
        if (PROD && tid == 0)
            release_flag(&g_flag0[b], (c + 1) * CH);
    }
}

// ---------------------------------------------------------------------------
// GEMM role (matvec formulation), 2 WGs per batch, half g owns rows
// [32g, 32g+32) of every chunk. Phase p: reduce row p-1 (+bias, store in
// place), MAC row p into the other buffer, one barrier. 33 phases/chunk.
// ---------------------------------------------------------------------------
__device__ __forceinline__ void gemm_phase(const float* rd, float* wr,
                                           float*& pw, const float* pr,
                                           float& xg, const float (&wreg)[4][32],
                                           float bsc, bool lane_lt32)
{
    float xg2 = *pr;                 // prefetch next row

    float s0 = rd[0 * PS], s1 = rd[1 * PS], s2 = rd[2 * PS], s3 = rd[3 * PS];
    float s = (s0 + s1) + (s2 + s3);
    s = fold32(s);
    if (lane_lt32) *pw = s + bsc;    // commit previous row

    mac_partials(xg, wreg, wr);      // partials for current row

    lds_barrier();
    xg = xg2;
    pw += HH;
}

__device__ void gemm_role(float* ws, const float* W,
                          const float* b1, const float* b2, float* sh,
                          int b, int half)
{
    float* pbufA = sh;
    float* pbufB = sh + 8 * PS;

    const int tid = threadIdx.x;
    const int w   = tid >> 6;
    const int l   = tid & 63;
    const int hf  = l >> 5;
    const int jr  = 32 * w + (l & 31);
    const bool lane_lt32 = (l < 32);

    float wreg[4][32];
    load_wreg(W, l, w, wreg);
    const float bsc = b1[jr] + b2[jr];

    const float* rdA = &pbufA[4 * hf * PS + jr];
    const float* rdB = &pbufB[4 * hf * PS + jr];
    float*       wrA = &pbufA[w * PS + 4 * l];
    float*       wrB = &pbufB[w * PS + 4 * l];

    int* myflag = half ? &g_flag1b[b] : &g_flag1[b];

#pragma unroll 1
    for (int c = 0; c < NCH; ++c) {
        wait_flag(&g_flag0[b], (c + 1) * CH);

        // my 32 rows of this chunk
        float* Ab = ws + ((size_t)b * Tt + (size_t)c * CH + 32 * half) * HH;

        // phase 0 (peeled): MAC row 0, no reduce/store
        float xg  = Ab[jr];              // row 0, fresh post-wait
        float xg2 = Ab[HH + jr];         // prefetch row 1
        mac_partials(xg, wreg, wrB);
        lds_barrier();
        xg = xg2;

        float* pw = Ab + jr;             // store ptr, starts at row 0
        const float* pr = Ab + 2 * HH + jr;   // prefetch ptr (row 2)

        // phases 1..30 (15 pairs)
#pragma unroll 1
        for (int p = 0; p < 15; ++p) {
            gemm_phase(rdB, wrA, pw, pr, xg, wreg, bsc, lane_lt32); pr += HH;
            gemm_phase(rdA, wrB, pw, pr, xg, wreg, bsc, lane_lt32); pr += HH;
        }
        // phase 31: prefetch clamped to row 31 (value discarded)
        gemm_phase(rdB, wrA, pw, pr - HH, xg, wreg, bsc, lane_lt32);

        // tail phase 32: reduce row 31 only; FULL sync drains stores
        {
            float s0 = rdA[0 * PS], s1 = rdA[1 * PS];
            float s2 = rdA[2 * PS], s3 = rdA[3 * PS];
            float s = (s0 + s1) + (s2 + s3);
            s = fold32(s);
            if (lane_lt32) *pw = s + bsc;
            __syncthreads();
        }

        if (tid == 0)
            release_flag(myflag, (c + 1) * (CH / 2));
    }
}

// ---------------------------------------------------------------------------
// Pipelined fused kernel, 256 WGs x 512 threads (full chip, 1 WG/CU):
//   blocks 0..63    producer (layer-0 recurrence)
//   blocks 64..191  gemm halves (2 per batch: b = (bid-64)>>1, half = &1)
//   blocks 192..255 consumer (layer-1 recurrence)
// Producers first in blockIdx order; wait graph is a DAG => no deadlock.
// ---------------------------------------------------------------------------
__global__ __launch_bounds__(512, 2) void pipeline_kernel(
        float* ws, const float* Whh0, const float* Wih1,
        const float* bih1, const float* bhh1, const float* Whh1)
{
    __shared__ __attribute__((aligned(16))) float sh[2 * 8 * PS];  // 16640 B

    const int bid = blockIdx.x;

    if (bid < 64) {
        rnn_role<true>(ws + (size_t)bid * Tt * HH, Whh0, sh, bid);
    } else if (bid < 192) {
        const int pidx = bid - 64;
        gemm_role(ws, Wih1, bih1, bhh1, sh, pidx >> 1, pidx & 1);
    } else {
        const int b = bid - 192;
        rnn_role<false>(ws + (size_t)b * Tt * HH, Whh1, sh, b);
    }
}

// ---------------------------------------------------------------------------
// FC: out[b] = dot(h2[b][T-1][:], W_fc) + b_fc.  One wave per batch.
// ---------------------------------------------------------------------------
__global__ __launch_bounds__(64) void fc_kernel(const float* h2, const float* Wfc,
                                                const float* bfc, float* out)
{
    const int b = blockIdx.x;
    const int l = threadIdx.x;
    const float* hrow = h2 + ((size_t)b * Tt + (Tt - 1)) * HH;
    float4 hv = *(const float4*)&hrow[4 * l];
    float4 wv = *(const float4*)&Wfc[4 * l];
    float p = hv.x * wv.x + hv.y * wv.y + hv.z * wv.z + hv.w * wv.w;
#pragma unroll
    for (int off = 32; off > 0; off >>= 1) p += __shfl_down(p, off, 64);
    if (l == 0) out[b] = p + bfc[0];
}

// ---------------------------------------------------------------------------
extern "C" void kernel_launch(void* const* d_in, const int* in_sizes, int n_in,
                              void* d_out, int out_size, void* d_ws, size_t ws_size,
                              hipStream_t stream)
{
    const float* x     = (const float*)d_in[0];
    const float* W_ih0 = (const float*)d_in[1];
    const float* W_hh0 = (const float*)d_in[2];
    const float* b_ih0 = (const float*)d_in[3];
    const float* b_hh0 = (const float*)d_in[4];
    const float* W_ih1 = (const float*)d_in[5];
    const float* W_hh1 = (const float*)d_in[6];
    const float* b_ih1 = (const float*)d_in[7];
    const float* b_hh1 = (const float*)d_in[8];
    const float* W_fc  = (const float*)d_in[9];
    const float* b_fc  = (const float*)d_in[10];
    float* ws  = (float*)d_ws;                 // B*T*H floats (128 MiB)
    float* out = (float*)d_out;

    // 1) xp0 = x @ W_ih0^T + b_ih0 + b_hh0  (+ zero pipeline flags)
    ih_gemm<<<ROWS / 64, 256, 0, stream>>>(x, W_ih0, b_ih0, b_hh0, ws);
    // 2) fused pipeline: L0 recurrence -> chunked xp1 matvec (2 WGs/batch)
    //    -> L1 recurrence, all in-place in ws; ws ends as the h2 sequence.
    pipeline_kernel<<<256, 512, 0, stream>>>(ws, W_hh0, W_ih1, b_ih1, b_hh1, W_hh1);
    // 3) out = h2[:, T-1, :] @ W_fc^T + b_fc
    fc_kernel<<<Bb, 64, 0, stream>>>(ws, W_fc, b_fc, out);
}